// Round 3
// baseline (1264.495 us; speedup 1.0000x reference)
//
#include <hip/hip_runtime.h>
#include <math.h>

#define B 8
#define C 128
#define H 160
#define W 160
#define HW 25600
#define WP 162   // padded width/height (pad=1 ring of zeros)

typedef short bf16x8 __attribute__((ext_vector_type(8)));
typedef float f32x4  __attribute__((ext_vector_type(4)));

__device__ __forceinline__ unsigned short f2bf(float x) {  // RNE
    union { float f; unsigned u; } v; v.f = x;
    unsigned r = v.u + 0x7fff + ((v.u >> 16) & 1);
    return (unsigned short)(r >> 16);
}
__device__ __forceinline__ float bf2f(unsigned short h) {
    union { unsigned u; float f; } v; v.u = ((unsigned)h) << 16;
    return v.f;
}

// ---------------- weight repack: split-bf16 [tap][co][ci] ----------------
__global__ void k_repack(const float* __restrict__ w1, const float* __restrict__ w2,
                         const float* __restrict__ w3, const float* __restrict__ dw,
                         const float* __restrict__ cw,
                         unsigned short* __restrict__ wpk1h, unsigned short* __restrict__ wpk1l,
                         unsigned short* __restrict__ wpk2h, unsigned short* __restrict__ wpk2l,
                         unsigned short* __restrict__ wpk3h, unsigned short* __restrict__ wpk3l,
                         float* __restrict__ wHT) {
    int idx = blockIdx.x * 256 + threadIdx.x;
    if (idx < 73728) {  // w1: [t][co=128][ci=64]  (ci 0..49 real, 50..63 zero)
        int t = idx / 8192; int r = idx % 8192; int co = r / 64; int ci = r % 64;
        float v = (ci < 50) ? w1[(co * 50 + ci) * 9 + t] : 0.f;
        unsigned short h = f2bf(v);
        wpk1h[idx] = h; wpk1l[idx] = f2bf(v - bf2f(h));
        return;
    }
    idx -= 73728;
    if (idx < 73728) {  // w2: [t][co=64][ci=128]
        int t = idx / 8192; int r = idx % 8192; int co = r / 128; int ci = r % 128;
        float v = w2[(co * 128 + ci) * 9 + t];
        unsigned short h = f2bf(v);
        wpk2h[idx] = h; wpk2l[idx] = f2bf(v - bf2f(h));
        return;
    }
    idx -= 73728;
    if (idx < 18432) {  // w3: [t][co=32][ci=64]
        int t = idx / 2048; int r = idx % 2048; int co = r / 64; int ci = r % 64;
        float v = w3[(co * 64 + ci) * 9 + t];
        unsigned short h = f2bf(v);
        wpk3h[idx] = h; wpk3l[idx] = f2bf(v - bf2f(h));
        return;
    }
    idx -= 18432;
    if (idx < 2400) {   // heads (fp32): wHT[ci][k][3]: 0,1=disp 2=conf
        int ci = idx / 75; int rem = idx % 75; int k = rem / 3; int co = rem % 3;
        wHT[idx] = (co < 2) ? dw[(co * 32 + ci) * 25 + k] : cw[ci * 25 + k];
    }
}

// ---------------- zero the pad rings of xin (C=64) and x1 (C=128) ----------------
__global__ void k_zeropad(unsigned short* __restrict__ xin_hi, unsigned short* __restrict__ xin_lo,
                          unsigned short* __restrict__ x1_hi,  unsigned short* __restrict__ x1_lo) {
    int idx = blockIdx.x * 256 + threadIdx.x;
    unsigned short *ph, *pl; int Cc;
    if (idx < 41216) { ph = xin_hi; pl = xin_lo; Cc = 64; }
    else {
        idx -= 41216;
        if (idx >= 82432) return;
        ph = x1_hi; pl = x1_lo; Cc = 128;
    }
    int chunks = Cc / 8;
    int img = idx / (644 * chunks);
    int r = idx % (644 * chunks);
    int rp = r / chunks; int ch = r % chunks;
    int yy, xx;
    if (rp < 162)      { yy = 0;   xx = rp; }
    else if (rp < 324) { yy = 161; xx = rp - 162; }
    else { int s = rp - 324; yy = 1 + (s >> 1); xx = (s & 1) ? 161 : 0; }
    size_t off = ((size_t)(img * WP + yy) * WP + xx) * Cc + ch * 8;
    bf16x8 z = {0, 0, 0, 0, 0, 0, 0, 0};
    *(bf16x8*)&ph[off] = z;
    *(bf16x8*)&pl[off] = z;
}

// ---------------- deconv upsample (stride 2, pad 1, k=4) ----------------
__global__ void k_upsample(const float* __restrict__ flow, const float* __restrict__ conf,
                           const float* __restrict__ up_flow_w, const float* __restrict__ up_conf_w,
                           float* __restrict__ flow_up,
                           unsigned short* __restrict__ xin_hi, unsigned short* __restrict__ xin_lo) {
    int idx = blockIdx.x * 256 + threadIdx.x;
    if (idx >= B * 3 * HW) return;
    int x = idx % W;
    int y = (idx / W) % H;
    int ch = (idx / HW) % 3;
    int b = idx / (3 * HW);
    const float* in;
    const float* w;
    if (ch < 2) { in = flow + (size_t)(b * 2 + ch) * 6400; w = up_flow_w + ch * 16; }
    else        { in = conf + (size_t)b * 6400;            w = up_conf_w; }
    float acc = 0.f;
#pragma unroll
    for (int dy = 0; dy < 4; ++dy) {
        int tny = y + 1 - dy;
        if (tny < 0 || (tny & 1)) continue;
        int iy = tny >> 1;
        if (iy >= 80) continue;
#pragma unroll
        for (int dx = 0; dx < 4; ++dx) {
            int tnx = x + 1 - dx;
            if (tnx < 0 || (tnx & 1)) continue;
            int ix = tnx >> 1;
            if (ix >= 80) continue;
            acc += in[iy * 80 + ix] * w[dy * 4 + dx];
        }
    }
    if (ch < 2) flow_up[(size_t)(b * 2 + ch) * HW + y * W + x] = acc;
    else {
        // conf is channel 49 of the padded NHWC(64) conv1 input
        size_t off = ((size_t)(b * WP + y + 1) * WP + (x + 1)) * 64 + 49;
        unsigned short h = f2bf(acc);
        xin_hi[off] = h;
        xin_lo[off] = f2bf(acc - bf2f(h));
    }
}

// ---------------- dilated self-correlation (PATCH=7, DIL=2), parity-packed ----------------
// Block: 32x16 pixel tile, 256 threads, 2 px/thread (x-pair x, x+2, same parity).
// LDS: 4 channels x 28 rows x [par*24 + x2] packed floats, row stride 49 words (odd,
// spreads banks). Stride-2 taps become consecutive packed floats -> ds_read2 merging:
// 7 rows x 8 floats + 1 center pair = ~29 LDS insts per 98 FMAs (was 100 per 49).
__global__ __launch_bounds__(256) void k_corr(const float* __restrict__ feats,
                                              unsigned short* __restrict__ xin_hi,
                                              unsigned short* __restrict__ xin_lo) {
    const int b = blockIdx.z;
    const int x0 = blockIdx.x * 32;
    const int y0 = blockIdx.y * 16;
    const int tid = threadIdx.x;
    const int tx = tid & 15;          // x-pair index
    const int ty = tid >> 4;          // row 0..15
    const int par = tx >> 3;          // global-x parity
    const int j = tx & 7;             // pair slot
    // pixels: pxA = x0 + 4j + par, pxB = pxA + 2
    __shared__ float sh[4][28 * 49];
    float accA[49], accB[49];
#pragma unroll
    for (int i = 0; i < 49; ++i) { accA[i] = 0.f; accB[i] = 0.f; }
    const float* f = feats + (size_t)b * 2 * C * HW;  // feats[b, 0]
    for (int c0 = 0; c0 < C; c0 += 4) {
        __syncthreads();
        for (int i = tid; i < 4 * 28 * 44; i += 256) {
            int cl = i / 1232;
            int rem = i - cl * 1232;
            int r = rem / 44, xp = rem % 44;
            int gy = y0 + r - 6, gx = x0 + xp - 6;
            float v = 0.f;
            if (gy >= 0 && gy < H && gx >= 0 && gx < W)
                v = f[(size_t)(c0 + cl) * HW + gy * W + gx];
            sh[cl][r * 49 + (xp & 1) * 24 + (xp >> 1)] = v;
        }
        __syncthreads();
#pragma unroll
        for (int cl = 0; cl < 4; ++cl) {
            const float* shc = sh[cl];
            const float* cp = &shc[(ty + 6) * 49 + par * 24 + 2 * j + 3];
            float cA = cp[0];
            float cB = cp[1];
#pragma unroll
            for (int dy = 0; dy < 7; ++dy) {
                const float* q = &shc[(ty + 2 * dy) * 49 + par * 24 + 2 * j];
                float w0 = q[0], w1 = q[1], w2 = q[2], w3 = q[3];
                float w4 = q[4], w5 = q[5], w6 = q[6], w7 = q[7];
                accA[dy * 7 + 0] += cA * w0;
                accA[dy * 7 + 1] += cA * w1;
                accA[dy * 7 + 2] += cA * w2;
                accA[dy * 7 + 3] += cA * w3;
                accA[dy * 7 + 4] += cA * w4;
                accA[dy * 7 + 5] += cA * w5;
                accA[dy * 7 + 6] += cA * w6;
                accB[dy * 7 + 0] += cB * w1;
                accB[dy * 7 + 1] += cB * w2;
                accB[dy * 7 + 2] += cB * w3;
                accB[dy * 7 + 3] += cB * w4;
                accB[dy * 7 + 4] += cB * w5;
                accB[dy * 7 + 5] += cB * w6;
                accB[dy * 7 + 6] += cB * w7;
            }
        }
    }
    const int y = y0 + ty;
    const int pxA = x0 + 4 * j + par;
    size_t pA = ((size_t)(b * WP + y + 1) * WP + (pxA + 1)) * 64;
    size_t pB = pA + 2 * 64;  // pxB = pxA + 2
#pragma unroll
    for (int k = 0; k < 49; ++k) {
        float vA = accA[k];
        vA = (vA > 0.f) ? vA : 0.1f * vA;
        vA *= 0.0078125f;
        unsigned short hA = f2bf(vA);
        xin_hi[pA + k] = hA;
        xin_lo[pA + k] = f2bf(vA - bf2f(hA));
        float vB = accB[k];
        vB = (vB > 0.f) ? vB : 0.1f * vB;
        vB *= 0.0078125f;
        unsigned short hB = f2bf(vB);
        xin_hi[pB + k] = hB;
        xin_lo[pB + k] = f2bf(vB - bf2f(hB));
    }
#pragma unroll
    for (int k = 50; k < 64; ++k) {
        xin_hi[pA + k] = 0; xin_lo[pA + k] = 0;
        xin_hi[pB + k] = 0; xin_lo[pB + k] = 0;
    }
}

// ---------------- split-bf16 MFMA 3x3 conv + bias + leaky_relu ----------------
// Implicit GEMM per tap. Wave = 80 px (5 m-tiles) x COB couts; grid.y splits cout so
// NT<=4 (acc<=80 VGPRs). Weights double-buffered: tap t+1 prefetched global->regs
// while computing tap t, so barriers only drain LDS writes.
template<int CIN, int COUT, int COB, int OUTF>
__global__ __launch_bounds__(256, 2) void k_convM(
    const unsigned short* __restrict__ in_hi, const unsigned short* __restrict__ in_lo,
    const unsigned short* __restrict__ w_hi,  const unsigned short* __restrict__ w_lo,
    const float* __restrict__ bias,
    unsigned short* __restrict__ out_hi, unsigned short* __restrict__ out_lo,
    float* __restrict__ out_f) {
    constexpr int NT = COB / 16;
    constexpr int PITCH = CIN + 8;
    constexpr int CH = CIN / 8;
    constexpr int NST = (COB * CH) / 256;  // staging iters (exact multiples)
    __shared__ unsigned short wl[2 * COB * PITCH];
    const int b = blockIdx.z;
    const int co0 = blockIdx.y * COB;
    const int wave = threadIdx.x >> 6;
    const int lane = threadIdx.x & 63;
    const int y = blockIdx.x * 2 + (wave >> 1);   // interior row 0..159
    const int x0 = (wave & 1) * 80;
    const int m = lane & 15, q = lane >> 4;
    f32x4 acc[5][NT];
#pragma unroll
    for (int mt = 0; mt < 5; ++mt)
#pragma unroll
        for (int nt = 0; nt < NT; ++nt) acc[mt][nt] = (f32x4){0.f, 0.f, 0.f, 0.f};
    int abase[5];
#pragma unroll
    for (int mt = 0; mt < 5; ++mt)
        abase[mt] = ((b * WP + y) * WP + x0 + mt * 16 + m) * CIN + q * 8;

    // prefetch tap 0 weights into regs
    bf16x8 rh[NST], rl[NST];
#pragma unroll
    for (int s = 0; s < NST; ++s) {
        int i = s * 256 + threadIdx.x;
        int co = i / CH, ch = i - co * CH;
        int src = (0 * COUT + co0 + co) * CIN + ch * 8;
        rh[s] = *(const bf16x8*)&w_hi[src];
        rl[s] = *(const bf16x8*)&w_lo[src];
    }

    for (int tap = 0; tap < 9; ++tap) {
        const int tapoff = ((tap / 3) * WP + (tap % 3)) * CIN;
        __syncthreads();
#pragma unroll
        for (int s = 0; s < NST; ++s) {
            int i = s * 256 + threadIdx.x;
            int co = i / CH, ch = i - co * CH;
            int dst = co * PITCH + ch * 8;
            *(bf16x8*)&wl[dst] = rh[s];
            *(bf16x8*)&wl[COB * PITCH + dst] = rl[s];
        }
        __syncthreads();
        if (tap < 8) {
#pragma unroll
            for (int s = 0; s < NST; ++s) {
                int i = s * 256 + threadIdx.x;
                int co = i / CH, ch = i - co * CH;
                int src = ((tap + 1) * COUT + co0 + co) * CIN + ch * 8;
                rh[s] = *(const bf16x8*)&w_hi[src];
                rl[s] = *(const bf16x8*)&w_lo[src];
            }
        }
#pragma unroll
        for (int kc = 0; kc < CIN / 32; ++kc) {
            bf16x8 ah[5], al[5];
#pragma unroll
            for (int mt = 0; mt < 5; ++mt) {
                const int off = abase[mt] + tapoff + kc * 32;
                ah[mt] = *(const bf16x8*)&in_hi[off];
                al[mt] = *(const bf16x8*)&in_lo[off];
            }
#pragma unroll
            for (int nt = 0; nt < NT; ++nt) {
                const int woff = (nt * 16 + m) * PITCH + kc * 32 + q * 8;
                bf16x8 bh = *(const bf16x8*)&wl[woff];
                bf16x8 bl = *(const bf16x8*)&wl[COB * PITCH + woff];
#pragma unroll
                for (int mt = 0; mt < 5; ++mt) {
                    acc[mt][nt] = __builtin_amdgcn_mfma_f32_16x16x32_bf16(ah[mt], bh, acc[mt][nt], 0, 0, 0);
                    acc[mt][nt] = __builtin_amdgcn_mfma_f32_16x16x32_bf16(ah[mt], bl, acc[mt][nt], 0, 0, 0);
                    acc[mt][nt] = __builtin_amdgcn_mfma_f32_16x16x32_bf16(al[mt], bh, acc[mt][nt], 0, 0, 0);
                }
            }
        }
    }
    // epilogue: D col = lane&15 = co, D row = q*4+r = pixel within m-tile
#pragma unroll
    for (int nt = 0; nt < NT; ++nt) {
        const int co = co0 + nt * 16 + m;
        const float bv = bias[co];
#pragma unroll
        for (int mt = 0; mt < 5; ++mt) {
#pragma unroll
            for (int r = 0; r < 4; ++r) {
                float v = acc[mt][nt][r] + bv;
                v = (v > 0.f) ? v : 0.1f * v;
                const int x = x0 + mt * 16 + q * 4 + r;
                if (OUTF) {
                    out_f[((size_t)(b * COUT + co)) * HW + y * W + x] = v;
                } else {
                    const size_t off = ((size_t)(b * WP + y + 1) * WP + (x + 1)) * COUT + co;
                    unsigned short h = f2bf(v);
                    out_hi[off] = h;
                    out_lo[off] = f2bf(v - bf2f(h));
                }
            }
        }
    }
}

// ---------------- fused heads (5x5 convs) + warp + sigmoid ----------------
__global__ __launch_bounds__(256) void k_head(const float* __restrict__ x3,
                                              const float* __restrict__ wHT,
                                              const float* __restrict__ disp_b,
                                              const float* __restrict__ conf_b,
                                              const float* __restrict__ flow_up,
                                              float* __restrict__ out) {
    const int b = blockIdx.z;
    const int x0 = blockIdx.x * 16, y0 = blockIdx.y * 16;
    const int tx = threadIdx.x, ty = threadIdx.y;
    const int tid = ty * 16 + tx;
    __shared__ float sh[2 * 400];  // 2 channels x 20x20
    float a0 = 0.f, a1 = 0.f, a2 = 0.f;
    const float* xb = x3 + (size_t)(b * 32) * HW;
    for (int ci = 0; ci < 32; ci += 2) {
        __syncthreads();
        for (int i = tid; i < 800; i += 256) {
            int cc = i / 400;
            int rem = i - cc * 400;
            int r = rem / 20, c2 = rem % 20;
            int gy = y0 + r - 2, gx = x0 + c2 - 2;
            float v = 0.f;
            if (gy >= 0 && gy < H && gx >= 0 && gx < W)
                v = xb[(size_t)(ci + cc) * HW + gy * W + gx];
            sh[i] = v;
        }
        __syncthreads();
#pragma unroll
        for (int cc = 0; cc < 2; ++cc) {
            const float* t = sh + cc * 400;
            const float* wp = wHT + (size_t)(ci + cc) * 75;
#pragma unroll
            for (int k = 0; k < 25; ++k) {
                float v = t[(ty + k / 5) * 20 + tx + (k % 5)];
                a0 += v * wp[k * 3 + 0];
                a1 += v * wp[k * 3 + 1];
                a2 += v * wp[k * 3 + 2];
            }
        }
    }
    const int gx = x0 + tx, gy = y0 + ty;
    float d0 = a0 + disp_b[0];
    float d1 = a1 + disp_b[1];
    float cf = a2 + conf_b[0];
    cf = 1.f / (1.f + expf(-cf));

    float px = (float)gx + d0, py = (float)gy + d1;
    float x0f = floorf(px), y0f = floorf(py);
    float wx1 = px - x0f, wx0 = 1.f - wx1;
    float wy1 = py - y0f, wy0 = 1.f - wy1;
    const float* f0 = flow_up + (size_t)(b * 2) * HW;
    const float* f1 = f0 + HW;

    float m00, m01, m10, m11;
    float a00, a01, a10, a11;
    float b00, b01, b10, b11;
    auto corner = [&](float xf, float yf, float& m, float& c0, float& c1) {
        bool valid = (xf >= 0.f) && (xf <= (float)(W - 1)) && (yf >= 0.f) && (yf <= (float)(H - 1));
        m = valid ? 1.f : 0.f;
        if (valid) {
            int xi = (int)xf, yi = (int)yf;
            int o = yi * W + xi;
            c0 = f0[o]; c1 = f1[o];
        } else { c0 = 0.f; c1 = 0.f; }
    };
    corner(x0f,       y0f,       m00, a00, b00);
    corner(x0f + 1.f, y0f,       m01, a01, b01);
    corner(x0f,       y0f + 1.f, m10, a10, b10);
    corner(x0f + 1.f, y0f + 1.f, m11, a11, b11);

    float o0 = wy0 * (wx0 * a00 + wx1 * a01) + wy1 * (wx0 * a10 + wx1 * a11);
    float o1 = wy0 * (wx0 * b00 + wx1 * b01) + wy1 * (wx0 * b10 + wx1 * b11);
    float msk = wy0 * (wx0 * m00 + wx1 * m01) + wy1 * (wx0 * m10 + wx1 * m11);
    float mask = (msk >= 1.f) ? 1.f : 0.f;

    int o = gy * W + gx;
    out[(size_t)(b * 2 + 0) * HW + o] = o0 * mask;
    out[(size_t)(b * 2 + 1) * HW + o] = o1 * mask;
    out[(size_t)B * 2 * HW + (size_t)b * HW + o] = cf;
}

extern "C" void kernel_launch(void* const* d_in, const int* in_sizes, int n_in,
                              void* d_out, int out_size, void* d_ws, size_t ws_size,
                              hipStream_t stream) {
    const float* feats     = (const float*)d_in[0];
    const float* flow      = (const float*)d_in[1];
    const float* conf      = (const float*)d_in[2];
    const float* up_conf_w = (const float*)d_in[3];
    const float* up_flow_w = (const float*)d_in[4];
    const float* w1        = (const float*)d_in[5];
    const float* b1        = (const float*)d_in[6];
    const float* w2        = (const float*)d_in[7];
    const float* b2        = (const float*)d_in[8];
    const float* w3        = (const float*)d_in[9];
    const float* b3        = (const float*)d_in[10];
    const float* disp_w    = (const float*)d_in[11];
    const float* disp_b    = (const float*)d_in[12];
    const float* conf_w    = (const float*)d_in[13];
    const float* conf_b    = (const float*)d_in[14];
    float* out = (float*)d_out;

    // workspace layout (bytes)
    char* p = (char*)d_ws;
    const size_t SZ_XIN = (size_t)B * WP * WP * 64 * 2;    // 26,873,856 per buffer
    const size_t SZ_X1  = (size_t)B * WP * WP * 128 * 2;   // 53,747,712 per buffer
    unsigned short* xin_hi = (unsigned short*)p;
    unsigned short* xin_lo = (unsigned short*)(p + SZ_XIN);
    unsigned short* x1_hi  = (unsigned short*)(p + 2 * SZ_XIN);
    unsigned short* x1_lo  = (unsigned short*)(p + 2 * SZ_XIN + SZ_X1);
    char* p2 = p + 2 * SZ_XIN + 2 * SZ_X1;
    float* flow_up = (float*)p2;                 // 1,638,400 B
    float* wHT     = (float*)(p2 + 1638400);     // 9,600 B
    unsigned short* wpk1h = (unsigned short*)(p2 + 1648000);
    unsigned short* wpk1l = wpk1h + 73728;
    unsigned short* wpk2h = wpk1l + 73728;
    unsigned short* wpk2l = wpk2h + 73728;
    unsigned short* wpk3h = wpk2l + 73728;
    unsigned short* wpk3l = wpk3h + 18432;
    // aliases: x2 reuses xin (same geometry C=64, ring stays zero); x3 reuses x1_hi
    unsigned short* x2_hi = xin_hi;
    unsigned short* x2_lo = xin_lo;
    float* x3 = (float*)(p + 2 * SZ_XIN);        // 26.2 MB <= SZ_X1, x1 dead after conv2

    k_repack<<<658, 256, 0, stream>>>(w1, w2, w3, disp_w, conf_w,
                                      wpk1h, wpk1l, wpk2h, wpk2l, wpk3h, wpk3l, wHT);
    k_zeropad<<<484, 256, 0, stream>>>(xin_hi, xin_lo, x1_hi, x1_lo);
    k_upsample<<<(B * 3 * HW + 255) / 256, 256, 0, stream>>>(flow, conf, up_flow_w, up_conf_w,
                                                             flow_up, xin_hi, xin_lo);
    k_corr<<<dim3(5, 10, B), 256, 0, stream>>>(feats, xin_hi, xin_lo);
    k_convM<64, 128, 64, 0><<<dim3(80, 2, B), 256, 0, stream>>>(xin_hi, xin_lo, wpk1h, wpk1l, b1,
                                                                x1_hi, x1_lo, nullptr);
    k_convM<128, 64, 64, 0><<<dim3(80, 1, B), 256, 0, stream>>>(x1_hi, x1_lo, wpk2h, wpk2l, b2,
                                                                x2_hi, x2_lo, nullptr);
    k_convM<64, 32, 32, 1><<<dim3(80, 1, B), 256, 0, stream>>>(x2_hi, x2_lo, wpk3h, wpk3l, b3,
                                                               nullptr, nullptr, x3);
    k_head<<<dim3(10, 10, B), dim3(16, 16), 0, stream>>>(x3, wHT, disp_b, conf_b, flow_up, out);
}

// Round 4
// 997.468 us; speedup vs baseline: 1.2677x; 1.2677x over previous
//
#include <hip/hip_runtime.h>
#include <math.h>

#define B 8
#define C 128
#define H 160
#define W 160
#define HW 25600
#define WP 162   // padded width/height (pad=1 ring of zeros)

typedef short bf16x8 __attribute__((ext_vector_type(8)));
typedef float f32x4  __attribute__((ext_vector_type(4)));

__device__ __forceinline__ unsigned short f2bf(float x) {  // RNE
    union { float f; unsigned u; } v; v.f = x;
    unsigned r = v.u + 0x7fff + ((v.u >> 16) & 1);
    return (unsigned short)(r >> 16);
}
__device__ __forceinline__ float bf2f(unsigned short h) {
    union { unsigned u; float f; } v; v.u = ((unsigned)h) << 16;
    return v.f;
}

// ---------------- weight repack: split-bf16 [tap][co][ci] ----------------
__global__ void k_repack(const float* __restrict__ w1, const float* __restrict__ w2,
                         const float* __restrict__ w3, const float* __restrict__ dw,
                         const float* __restrict__ cw,
                         unsigned short* __restrict__ wpk1h, unsigned short* __restrict__ wpk1l,
                         unsigned short* __restrict__ wpk2h, unsigned short* __restrict__ wpk2l,
                         unsigned short* __restrict__ wpk3h, unsigned short* __restrict__ wpk3l,
                         float* __restrict__ wHT) {
    int idx = blockIdx.x * 256 + threadIdx.x;
    if (idx < 73728) {  // w1: [t][co=128][ci=64]  (ci 0..49 real, 50..63 zero)
        int t = idx / 8192; int r = idx % 8192; int co = r / 64; int ci = r % 64;
        float v = (ci < 50) ? w1[(co * 50 + ci) * 9 + t] : 0.f;
        unsigned short h = f2bf(v);
        wpk1h[idx] = h; wpk1l[idx] = f2bf(v - bf2f(h));
        return;
    }
    idx -= 73728;
    if (idx < 73728) {  // w2: [t][co=64][ci=128]
        int t = idx / 8192; int r = idx % 8192; int co = r / 128; int ci = r % 128;
        float v = w2[(co * 128 + ci) * 9 + t];
        unsigned short h = f2bf(v);
        wpk2h[idx] = h; wpk2l[idx] = f2bf(v - bf2f(h));
        return;
    }
    idx -= 73728;
    if (idx < 18432) {  // w3: [t][co=32][ci=64]
        int t = idx / 2048; int r = idx % 2048; int co = r / 64; int ci = r % 64;
        float v = w3[(co * 64 + ci) * 9 + t];
        unsigned short h = f2bf(v);
        wpk3h[idx] = h; wpk3l[idx] = f2bf(v - bf2f(h));
        return;
    }
    idx -= 18432;
    if (idx < 2400) {   // heads (fp32): wHT[ci][k][3]: 0,1=disp 2=conf
        int ci = idx / 75; int rem = idx % 75; int k = rem / 3; int co = rem % 3;
        wHT[idx] = (co < 2) ? dw[(co * 32 + ci) * 25 + k] : cw[ci * 25 + k];
    }
}

// ---------------- zero the pad rings of xin (C=64) and x1 (C=128) ----------------
__global__ void k_zeropad(unsigned short* __restrict__ xin_hi, unsigned short* __restrict__ xin_lo,
                          unsigned short* __restrict__ x1_hi,  unsigned short* __restrict__ x1_lo) {
    int idx = blockIdx.x * 256 + threadIdx.x;
    unsigned short *ph, *pl; int Cc;
    if (idx < 41216) { ph = xin_hi; pl = xin_lo; Cc = 64; }
    else {
        idx -= 41216;
        if (idx >= 82432) return;
        ph = x1_hi; pl = x1_lo; Cc = 128;
    }
    int chunks = Cc / 8;
    int img = idx / (644 * chunks);
    int r = idx % (644 * chunks);
    int rp = r / chunks; int ch = r % chunks;
    int yy, xx;
    if (rp < 162)      { yy = 0;   xx = rp; }
    else if (rp < 324) { yy = 161; xx = rp - 162; }
    else { int s = rp - 324; yy = 1 + (s >> 1); xx = (s & 1) ? 161 : 0; }
    size_t off = ((size_t)(img * WP + yy) * WP + xx) * Cc + ch * 8;
    bf16x8 z = {0, 0, 0, 0, 0, 0, 0, 0};
    *(bf16x8*)&ph[off] = z;
    *(bf16x8*)&pl[off] = z;
}

// ---------------- deconv upsample (stride 2, pad 1, k=4) ----------------
__global__ void k_upsample(const float* __restrict__ flow, const float* __restrict__ conf,
                           const float* __restrict__ up_flow_w, const float* __restrict__ up_conf_w,
                           float* __restrict__ flow_up,
                           unsigned short* __restrict__ xin_hi, unsigned short* __restrict__ xin_lo) {
    int idx = blockIdx.x * 256 + threadIdx.x;
    if (idx >= B * 3 * HW) return;
    int x = idx % W;
    int y = (idx / W) % H;
    int ch = (idx / HW) % 3;
    int b = idx / (3 * HW);
    const float* in;
    const float* w;
    if (ch < 2) { in = flow + (size_t)(b * 2 + ch) * 6400; w = up_flow_w + ch * 16; }
    else        { in = conf + (size_t)b * 6400;            w = up_conf_w; }
    float acc = 0.f;
#pragma unroll
    for (int dy = 0; dy < 4; ++dy) {
        int tny = y + 1 - dy;
        if (tny < 0 || (tny & 1)) continue;
        int iy = tny >> 1;
        if (iy >= 80) continue;
#pragma unroll
        for (int dx = 0; dx < 4; ++dx) {
            int tnx = x + 1 - dx;
            if (tnx < 0 || (tnx & 1)) continue;
            int ix = tnx >> 1;
            if (ix >= 80) continue;
            acc += in[iy * 80 + ix] * w[dy * 4 + dx];
        }
    }
    if (ch < 2) flow_up[(size_t)(b * 2 + ch) * HW + y * W + x] = acc;
    else {
        // conf is channel 49 of the padded NHWC(64) conv1 input
        size_t off = ((size_t)(b * WP + y + 1) * WP + (x + 1)) * 64 + 49;
        unsigned short h = f2bf(acc);
        xin_hi[off] = h;
        xin_lo[off] = f2bf(acc - bf2f(h));
    }
}

// ---------------- dilated self-correlation (PATCH=7, DIL=2) ----------------
// r2 compute structure (1 px/thread, acc[49]) + double-buffered channel staging:
// channel-invariant offsets precomputed, c+1 prefetched to regs during compute of c,
// ONE barrier per channel. 1-D grid, img = bid%8 pins each image to one XCD.
__global__ __launch_bounds__(256, 4) void k_corr(const float* __restrict__ feats,
                                                 unsigned short* __restrict__ xin_hi,
                                                 unsigned short* __restrict__ xin_lo) {
    const int bid = blockIdx.x;
    const int b = bid & 7;
    const int t = bid >> 3;           // 0..99
    const int x0 = (t % 5) * 32;
    const int y0 = (t / 5) * 8;
    const int tid = threadIdx.x;
    const int tx = tid & 31;
    const int ty = tid >> 5;          // 0..7
    __shared__ float sh[2][880];      // 20 rows x 44 cols, double-buffered
    float acc[49];
#pragma unroll
    for (int i = 0; i < 49; ++i) acc[i] = 0.f;

    // staging slots: channel-invariant
    int soff[4]; bool sval[4];
#pragma unroll
    for (int s = 0; s < 4; ++s) {
        int i = tid + s * 256;
        int r = i / 44, cc = i % 44;
        int gy = y0 + r - 6, gx = x0 + cc - 6;
        sval[s] = (i < 880) && gy >= 0 && gy < H && gx >= 0 && gx < W;
        soff[s] = sval[s] ? (gy * W + gx) : 0;
    }
    const float* f = feats + (size_t)b * 2 * C * HW;  // feats[b, 0]
    float pre[4];
#pragma unroll
    for (int s = 0; s < 4; ++s) pre[s] = sval[s] ? f[soff[s]] : 0.f;

    for (int c = 0; c < C; ++c) {
        float* buf = sh[c & 1];
#pragma unroll
        for (int s = 0; s < 4; ++s) {
            int i = tid + s * 256;
            if (i < 880) buf[i] = pre[s];
        }
        if (c < C - 1) {
            const float* fn = f + (size_t)(c + 1) * HW;
#pragma unroll
            for (int s = 0; s < 4; ++s) pre[s] = sval[s] ? fn[soff[s]] : 0.f;
        }
        __syncthreads();
        float ctr = buf[(ty + 6) * 44 + tx + 6];
#pragma unroll
        for (int dy = 0; dy < 7; ++dy) {
            const float* row = &buf[(ty + 2 * dy) * 44 + tx];
#pragma unroll
            for (int dx = 0; dx < 7; ++dx)
                acc[dy * 7 + dx] += ctr * row[2 * dx];
        }
        // no trailing barrier: next round writes the OTHER buffer; same-buffer
        // reuse at c+2 is ordered by the (c+1) barrier (compute-c precedes it).
    }
    size_t pbase = ((size_t)(b * WP + y0 + ty + 1) * WP + (x0 + tx + 1)) * 64;
#pragma unroll
    for (int k = 0; k < 49; ++k) {
        float v = acc[k];
        v = (v > 0.f) ? v : 0.1f * v;           // leaky_relu(0.1)
        v *= 0.0078125f;                        // / 128
        unsigned short h = f2bf(v);
        xin_hi[pbase + k] = h;
        xin_lo[pbase + k] = f2bf(v - bf2f(h));
    }
#pragma unroll
    for (int k = 50; k < 64; ++k) { xin_hi[pbase + k] = 0; xin_lo[pbase + k] = 0; }
}

// ---------------- split-bf16 MFMA 3x3 conv + bias + leaky_relu ----------------
// Implicit GEMM per tap, A-frags from global (L2-resident via XCD pinning:
// img = bid%8 -> all blocks of one image land on one XCD; concurrent working
// set ~2.8 MB < 4 MiB XCD-L2, so the 9x tap re-read hits L2 instead of HBM).
template<int CIN, int COUT, int COB, int NCO, int OUTF>
__global__ __launch_bounds__(256, 2) void k_convM(
    const unsigned short* __restrict__ in_hi, const unsigned short* __restrict__ in_lo,
    const unsigned short* __restrict__ w_hi,  const unsigned short* __restrict__ w_lo,
    const float* __restrict__ bias,
    unsigned short* __restrict__ out_hi, unsigned short* __restrict__ out_lo,
    float* __restrict__ out_f) {
    constexpr int NT = COB / 16;
    constexpr int PITCH = CIN + 8;
    constexpr int CH = CIN / 8;
    constexpr int NST = (COB * CH) / 256;  // staging iters (exact multiples)
    __shared__ unsigned short wl[2 * COB * PITCH];
    const int bid = blockIdx.x;
    const int b = bid & 7;
    const int t = bid >> 3;
    const int co0 = (t % NCO) * COB;
    const int ybx = t / NCO;
    const int wave = threadIdx.x >> 6;
    const int lane = threadIdx.x & 63;
    const int y = ybx * 2 + (wave >> 1);   // interior row 0..159
    const int x0 = (wave & 1) * 80;
    const int m = lane & 15, q = lane >> 4;
    f32x4 acc[5][NT];
#pragma unroll
    for (int mt = 0; mt < 5; ++mt)
#pragma unroll
        for (int nt = 0; nt < NT; ++nt) acc[mt][nt] = (f32x4){0.f, 0.f, 0.f, 0.f};
    int abase[5];
#pragma unroll
    for (int mt = 0; mt < 5; ++mt)
        abase[mt] = ((b * WP + y) * WP + x0 + mt * 16 + m) * CIN + q * 8;

    // prefetch tap 0 weights into regs
    bf16x8 rh[NST], rl[NST];
#pragma unroll
    for (int s = 0; s < NST; ++s) {
        int i = s * 256 + threadIdx.x;
        int co = i / CH, ch = i - co * CH;
        int src = (0 * COUT + co0 + co) * CIN + ch * 8;
        rh[s] = *(const bf16x8*)&w_hi[src];
        rl[s] = *(const bf16x8*)&w_lo[src];
    }

    for (int tap = 0; tap < 9; ++tap) {
        const int tapoff = ((tap / 3) * WP + (tap % 3)) * CIN;
        __syncthreads();
#pragma unroll
        for (int s = 0; s < NST; ++s) {
            int i = s * 256 + threadIdx.x;
            int co = i / CH, ch = i - co * CH;
            int dst = co * PITCH + ch * 8;
            *(bf16x8*)&wl[dst] = rh[s];
            *(bf16x8*)&wl[COB * PITCH + dst] = rl[s];
        }
        __syncthreads();
        if (tap < 8) {
#pragma unroll
            for (int s = 0; s < NST; ++s) {
                int i = s * 256 + threadIdx.x;
                int co = i / CH, ch = i - co * CH;
                int src = ((tap + 1) * COUT + co0 + co) * CIN + ch * 8;
                rh[s] = *(const bf16x8*)&w_hi[src];
                rl[s] = *(const bf16x8*)&w_lo[src];
            }
        }
#pragma unroll
        for (int kc = 0; kc < CIN / 32; ++kc) {
            bf16x8 ah[5], al[5];
#pragma unroll
            for (int mt = 0; mt < 5; ++mt) {
                const int off = abase[mt] + tapoff + kc * 32;
                ah[mt] = *(const bf16x8*)&in_hi[off];
                al[mt] = *(const bf16x8*)&in_lo[off];
            }
#pragma unroll
            for (int nt = 0; nt < NT; ++nt) {
                const int woff = (nt * 16 + m) * PITCH + kc * 32 + q * 8;
                bf16x8 bh = *(const bf16x8*)&wl[woff];
                bf16x8 bl = *(const bf16x8*)&wl[COB * PITCH + woff];
#pragma unroll
                for (int mt = 0; mt < 5; ++mt) {
                    acc[mt][nt] = __builtin_amdgcn_mfma_f32_16x16x32_bf16(ah[mt], bh, acc[mt][nt], 0, 0, 0);
                    acc[mt][nt] = __builtin_amdgcn_mfma_f32_16x16x32_bf16(ah[mt], bl, acc[mt][nt], 0, 0, 0);
                    acc[mt][nt] = __builtin_amdgcn_mfma_f32_16x16x32_bf16(al[mt], bh, acc[mt][nt], 0, 0, 0);
                }
            }
        }
    }
    // epilogue: D col = lane&15 = co, D row = q*4+r = pixel within m-tile
#pragma unroll
    for (int nt = 0; nt < NT; ++nt) {
        const int co = co0 + nt * 16 + m;
        const float bv = bias[co];
#pragma unroll
        for (int mt = 0; mt < 5; ++mt) {
#pragma unroll
            for (int r = 0; r < 4; ++r) {
                float v = acc[mt][nt][r] + bv;
                v = (v > 0.f) ? v : 0.1f * v;
                const int x = x0 + mt * 16 + q * 4 + r;
                if (OUTF) {
                    out_f[((size_t)(b * COUT + co)) * HW + y * W + x] = v;
                } else {
                    const size_t off = ((size_t)(b * WP + y + 1) * WP + (x + 1)) * COUT + co;
                    unsigned short h = f2bf(v);
                    out_hi[off] = h;
                    out_lo[off] = f2bf(v - bf2f(h));
                }
            }
        }
    }
}

// ---------------- fused heads (5x5 convs) + warp + sigmoid ----------------
__global__ __launch_bounds__(256) void k_head(const float* __restrict__ x3,
                                              const float* __restrict__ wHT,
                                              const float* __restrict__ disp_b,
                                              const float* __restrict__ conf_b,
                                              const float* __restrict__ flow_up,
                                              float* __restrict__ out) {
    const int bid = blockIdx.x;
    const int b = bid & 7;
    const int t = bid >> 3;           // 0..99
    const int x0 = (t % 10) * 16, y0 = (t / 10) * 16;
    const int tx = threadIdx.x & 15, ty = threadIdx.x >> 4;
    const int tid = threadIdx.x;
    __shared__ float sh[2 * 400];  // 2 channels x 20x20
    float a0 = 0.f, a1 = 0.f, a2 = 0.f;
    const float* xb = x3 + (size_t)(b * 32) * HW;
    for (int ci = 0; ci < 32; ci += 2) {
        __syncthreads();
        for (int i = tid; i < 800; i += 256) {
            int cc = i / 400;
            int rem = i - cc * 400;
            int r = rem / 20, c2 = rem % 20;
            int gy = y0 + r - 2, gx = x0 + c2 - 2;
            float v = 0.f;
            if (gy >= 0 && gy < H && gx >= 0 && gx < W)
                v = xb[(size_t)(ci + cc) * HW + gy * W + gx];
            sh[i] = v;
        }
        __syncthreads();
#pragma unroll
        for (int cc = 0; cc < 2; ++cc) {
            const float* t2 = sh + cc * 400;
            const float* wp = wHT + (size_t)(ci + cc) * 75;
#pragma unroll
            for (int k = 0; k < 25; ++k) {
                float v = t2[(ty + k / 5) * 20 + tx + (k % 5)];
                a0 += v * wp[k * 3 + 0];
                a1 += v * wp[k * 3 + 1];
                a2 += v * wp[k * 3 + 2];
            }
        }
    }
    const int gx = x0 + tx, gy = y0 + ty;
    float d0 = a0 + disp_b[0];
    float d1 = a1 + disp_b[1];
    float cf = a2 + conf_b[0];
    cf = 1.f / (1.f + expf(-cf));

    float px = (float)gx + d0, py = (float)gy + d1;
    float x0f = floorf(px), y0f = floorf(py);
    float wx1 = px - x0f, wx0 = 1.f - wx1;
    float wy1 = py - y0f, wy0 = 1.f - wy1;
    const float* f0 = flow_up + (size_t)(b * 2) * HW;
    const float* f1 = f0 + HW;

    float m00, m01, m10, m11;
    float a00, a01, a10, a11;
    float b00, b01, b10, b11;
    auto corner = [&](float xf, float yf, float& m, float& c0, float& c1) {
        bool valid = (xf >= 0.f) && (xf <= (float)(W - 1)) && (yf >= 0.f) && (yf <= (float)(H - 1));
        m = valid ? 1.f : 0.f;
        if (valid) {
            int xi = (int)xf, yi = (int)yf;
            int o = yi * W + xi;
            c0 = f0[o]; c1 = f1[o];
        } else { c0 = 0.f; c1 = 0.f; }
    };
    corner(x0f,       y0f,       m00, a00, b00);
    corner(x0f + 1.f, y0f,       m01, a01, b01);
    corner(x0f,       y0f + 1.f, m10, a10, b10);
    corner(x0f + 1.f, y0f + 1.f, m11, a11, b11);

    float o0 = wy0 * (wx0 * a00 + wx1 * a01) + wy1 * (wx0 * a10 + wx1 * a11);
    float o1 = wy0 * (wx0 * b00 + wx1 * b01) + wy1 * (wx0 * b10 + wx1 * b11);
    float msk = wy0 * (wx0 * m00 + wx1 * m01) + wy1 * (wx0 * m10 + wx1 * m11);
    float mask = (msk >= 1.f) ? 1.f : 0.f;

    int o = gy * W + gx;
    out[(size_t)(b * 2 + 0) * HW + o] = o0 * mask;
    out[(size_t)(b * 2 + 1) * HW + o] = o1 * mask;
    out[(size_t)B * 2 * HW + (size_t)b * HW + o] = cf;
}

extern "C" void kernel_launch(void* const* d_in, const int* in_sizes, int n_in,
                              void* d_out, int out_size, void* d_ws, size_t ws_size,
                              hipStream_t stream) {
    const float* feats     = (const float*)d_in[0];
    const float* flow      = (const float*)d_in[1];
    const float* conf      = (const float*)d_in[2];
    const float* up_conf_w = (const float*)d_in[3];
    const float* up_flow_w = (const float*)d_in[4];
    const float* w1        = (const float*)d_in[5];
    const float* b1        = (const float*)d_in[6];
    const float* w2        = (const float*)d_in[7];
    const float* b2        = (const float*)d_in[8];
    const float* w3        = (const float*)d_in[9];
    const float* b3        = (const float*)d_in[10];
    const float* disp_w    = (const float*)d_in[11];
    const float* disp_b    = (const float*)d_in[12];
    const float* conf_w    = (const float*)d_in[13];
    const float* conf_b    = (const float*)d_in[14];
    float* out = (float*)d_out;

    // workspace layout (bytes)
    char* p = (char*)d_ws;
    const size_t SZ_XIN = (size_t)B * WP * WP * 64 * 2;    // 26,873,856 per buffer
    const size_t SZ_X1  = (size_t)B * WP * WP * 128 * 2;   // 53,747,712 per buffer
    unsigned short* xin_hi = (unsigned short*)p;
    unsigned short* xin_lo = (unsigned short*)(p + SZ_XIN);
    unsigned short* x1_hi  = (unsigned short*)(p + 2 * SZ_XIN);
    unsigned short* x1_lo  = (unsigned short*)(p + 2 * SZ_XIN + SZ_X1);
    char* p2 = p + 2 * SZ_XIN + 2 * SZ_X1;
    float* flow_up = (float*)p2;                 // 1,638,400 B
    float* wHT     = (float*)(p2 + 1638400);     // 9,600 B
    unsigned short* wpk1h = (unsigned short*)(p2 + 1648000);
    unsigned short* wpk1l = wpk1h + 73728;
    unsigned short* wpk2h = wpk1l + 73728;
    unsigned short* wpk2l = wpk2h + 73728;
    unsigned short* wpk3h = wpk2l + 73728;
    unsigned short* wpk3l = wpk3h + 18432;
    // aliases: x2 reuses xin (same geometry C=64, ring stays zero); x3 reuses x1_hi
    unsigned short* x2_hi = xin_hi;
    unsigned short* x2_lo = xin_lo;
    float* x3 = (float*)(p + 2 * SZ_XIN);        // 26.2 MB <= SZ_X1, x1 dead after conv2

    k_repack<<<658, 256, 0, stream>>>(w1, w2, w3, disp_w, conf_w,
                                      wpk1h, wpk1l, wpk2h, wpk2l, wpk3h, wpk3l, wHT);
    k_zeropad<<<484, 256, 0, stream>>>(xin_hi, xin_lo, x1_hi, x1_lo);
    k_upsample<<<(B * 3 * HW + 255) / 256, 256, 0, stream>>>(flow, conf, up_flow_w, up_conf_w,
                                                             flow_up, xin_hi, xin_lo);
    // 1-D grids: img = bid%8 pins each image to one XCD (round-robin dispatch)
    k_corr<<<800, 256, 0, stream>>>(feats, xin_hi, xin_lo);
    k_convM<64, 128, 64, 2, 0><<<1280, 256, 0, stream>>>(xin_hi, xin_lo, wpk1h, wpk1l, b1,
                                                         x1_hi, x1_lo, nullptr);
    k_convM<128, 64, 64, 1, 0><<<640, 256, 0, stream>>>(x1_hi, x1_lo, wpk2h, wpk2l, b2,
                                                        x2_hi, x2_lo, nullptr);
    k_convM<64, 32, 32, 1, 1><<<640, 256, 0, stream>>>(x2_hi, x2_lo, wpk3h, wpk3l, b3,
                                                       nullptr, nullptr, x3);
    k_head<<<800, 256, 0, stream>>>(x3, wHT, disp_b, conf_b, flow_up, out);
}

// Round 5
// 953.281 us; speedup vs baseline: 1.3265x; 1.0464x over previous
//
#include <hip/hip_runtime.h>
#include <math.h>

#define B 8
#define C 128
#define H 160
#define W 160
#define HW 25600
#define WP 162   // padded width/height (pad=1 ring of zeros)

typedef short bf16x8 __attribute__((ext_vector_type(8)));
typedef float f32x4  __attribute__((ext_vector_type(4)));

__device__ __forceinline__ unsigned short f2bf(float x) {  // RNE
    union { float f; unsigned u; } v; v.f = x;
    unsigned r = v.u + 0x7fff + ((v.u >> 16) & 1);
    return (unsigned short)(r >> 16);
}
__device__ __forceinline__ float bf2f(unsigned short h) {
    union { unsigned u; float f; } v; v.u = ((unsigned)h) << 16;
    return v.f;
}

// ---------------- weight repack: split-bf16 [tap][co][ci] ----------------
__global__ void k_repack(const float* __restrict__ w1, const float* __restrict__ w2,
                         const float* __restrict__ w3, const float* __restrict__ dw,
                         const float* __restrict__ cw,
                         unsigned short* __restrict__ wpk1h, unsigned short* __restrict__ wpk1l,
                         unsigned short* __restrict__ wpk2h, unsigned short* __restrict__ wpk2l,
                         unsigned short* __restrict__ wpk3h, unsigned short* __restrict__ wpk3l,
                         float* __restrict__ wHT) {
    int idx = blockIdx.x * 256 + threadIdx.x;
    if (idx < 73728) {  // w1: [t][co=128][ci=64]  (ci 0..49 real, 50..63 zero)
        int t = idx / 8192; int r = idx % 8192; int co = r / 64; int ci = r % 64;
        float v = (ci < 50) ? w1[(co * 50 + ci) * 9 + t] : 0.f;
        unsigned short h = f2bf(v);
        wpk1h[idx] = h; wpk1l[idx] = f2bf(v - bf2f(h));
        return;
    }
    idx -= 73728;
    if (idx < 73728) {  // w2: [t][co=64][ci=128]
        int t = idx / 8192; int r = idx % 8192; int co = r / 128; int ci = r % 128;
        float v = w2[(co * 128 + ci) * 9 + t];
        unsigned short h = f2bf(v);
        wpk2h[idx] = h; wpk2l[idx] = f2bf(v - bf2f(h));
        return;
    }
    idx -= 73728;
    if (idx < 18432) {  // w3: [t][co=32][ci=64]
        int t = idx / 2048; int r = idx % 2048; int co = r / 64; int ci = r % 64;
        float v = w3[(co * 64 + ci) * 9 + t];
        unsigned short h = f2bf(v);
        wpk3h[idx] = h; wpk3l[idx] = f2bf(v - bf2f(h));
        return;
    }
    idx -= 18432;
    if (idx < 2400) {   // heads (fp32): wHT[ci][k][3]: 0,1=disp 2=conf
        int ci = idx / 75; int rem = idx % 75; int k = rem / 3; int co = rem % 3;
        wHT[idx] = (co < 2) ? dw[(co * 32 + ci) * 25 + k] : cw[ci * 25 + k];
    }
}

// ---------------- zero the pad rings of xin (C=64) and x1 (C=128) ----------------
__global__ void k_zeropad(unsigned short* __restrict__ xin_hi, unsigned short* __restrict__ xin_lo,
                          unsigned short* __restrict__ x1_hi,  unsigned short* __restrict__ x1_lo) {
    int idx = blockIdx.x * 256 + threadIdx.x;
    unsigned short *ph, *pl; int Cc;
    if (idx < 41216) { ph = xin_hi; pl = xin_lo; Cc = 64; }
    else {
        idx -= 41216;
        if (idx >= 82432) return;
        ph = x1_hi; pl = x1_lo; Cc = 128;
    }
    int chunks = Cc / 8;
    int img = idx / (644 * chunks);
    int r = idx % (644 * chunks);
    int rp = r / chunks; int ch = r % chunks;
    int yy, xx;
    if (rp < 162)      { yy = 0;   xx = rp; }
    else if (rp < 324) { yy = 161; xx = rp - 162; }
    else { int s = rp - 324; yy = 1 + (s >> 1); xx = (s & 1) ? 161 : 0; }
    size_t off = ((size_t)(img * WP + yy) * WP + xx) * Cc + ch * 8;
    bf16x8 z = {0, 0, 0, 0, 0, 0, 0, 0};
    *(bf16x8*)&ph[off] = z;
    *(bf16x8*)&pl[off] = z;
}

// ---------------- deconv upsample (stride 2, pad 1, k=4) ----------------
__global__ void k_upsample(const float* __restrict__ flow, const float* __restrict__ conf,
                           const float* __restrict__ up_flow_w, const float* __restrict__ up_conf_w,
                           float* __restrict__ flow_up,
                           unsigned short* __restrict__ xin_hi, unsigned short* __restrict__ xin_lo) {
    int idx = blockIdx.x * 256 + threadIdx.x;
    if (idx >= B * 3 * HW) return;
    int x = idx % W;
    int y = (idx / W) % H;
    int ch = (idx / HW) % 3;
    int b = idx / (3 * HW);
    const float* in;
    const float* w;
    if (ch < 2) { in = flow + (size_t)(b * 2 + ch) * 6400; w = up_flow_w + ch * 16; }
    else        { in = conf + (size_t)b * 6400;            w = up_conf_w; }
    float acc = 0.f;
#pragma unroll
    for (int dy = 0; dy < 4; ++dy) {
        int tny = y + 1 - dy;
        if (tny < 0 || (tny & 1)) continue;
        int iy = tny >> 1;
        if (iy >= 80) continue;
#pragma unroll
        for (int dx = 0; dx < 4; ++dx) {
            int tnx = x + 1 - dx;
            if (tnx < 0 || (tnx & 1)) continue;
            int ix = tnx >> 1;
            if (ix >= 80) continue;
            acc += in[iy * 80 + ix] * w[dy * 4 + dx];
        }
    }
    if (ch < 2) flow_up[(size_t)(b * 2 + ch) * HW + y * W + x] = acc;
    else {
        // conf is channel 49 of the padded NHWC(64) conv1 input
        size_t off = ((size_t)(b * WP + y + 1) * WP + (x + 1)) * 64 + 49;
        unsigned short h = f2bf(acc);
        xin_hi[off] = h;
        xin_lo[off] = f2bf(acc - bf2f(h));
    }
}

// ---------------- dilated self-correlation (PATCH=7, DIL=2) ----------------
// 1 px/thread, acc[49], double-buffered channel staging, ONE barrier/channel.
// img = bid%8 pins each image to one XCD.
__global__ __launch_bounds__(256, 4) void k_corr(const float* __restrict__ feats,
                                                 unsigned short* __restrict__ xin_hi,
                                                 unsigned short* __restrict__ xin_lo) {
    const int bid = blockIdx.x;
    const int b = bid & 7;
    const int t = bid >> 3;           // 0..99
    const int x0 = (t % 5) * 32;
    const int y0 = (t / 5) * 8;
    const int tid = threadIdx.x;
    const int tx = tid & 31;
    const int ty = tid >> 5;          // 0..7
    __shared__ float sh[2][880];      // 20 rows x 44 cols, double-buffered
    float acc[49];
#pragma unroll
    for (int i = 0; i < 49; ++i) acc[i] = 0.f;

    // staging slots: channel-invariant
    int soff[4]; bool sval[4];
#pragma unroll
    for (int s = 0; s < 4; ++s) {
        int i = tid + s * 256;
        int r = i / 44, cc = i % 44;
        int gy = y0 + r - 6, gx = x0 + cc - 6;
        sval[s] = (i < 880) && gy >= 0 && gy < H && gx >= 0 && gx < W;
        soff[s] = sval[s] ? (gy * W + gx) : 0;
    }
    const float* f = feats + (size_t)b * 2 * C * HW;  // feats[b, 0]
    float pre[4];
#pragma unroll
    for (int s = 0; s < 4; ++s) pre[s] = sval[s] ? f[soff[s]] : 0.f;

    for (int c = 0; c < C; ++c) {
        float* buf = sh[c & 1];
#pragma unroll
        for (int s = 0; s < 4; ++s) {
            int i = tid + s * 256;
            if (i < 880) buf[i] = pre[s];
        }
        if (c < C - 1) {
            const float* fn = f + (size_t)(c + 1) * HW;
#pragma unroll
            for (int s = 0; s < 4; ++s) pre[s] = sval[s] ? fn[soff[s]] : 0.f;
        }
        __syncthreads();
        float ctr = buf[(ty + 6) * 44 + tx + 6];
#pragma unroll
        for (int dy = 0; dy < 7; ++dy) {
            const float* row = &buf[(ty + 2 * dy) * 44 + tx];
#pragma unroll
            for (int dx = 0; dx < 7; ++dx)
                acc[dy * 7 + dx] += ctr * row[2 * dx];
        }
        // no trailing barrier: next round writes the OTHER buffer; same-buffer
        // reuse at c+2 is ordered by the (c+1) barrier (compute-c precedes it).
    }
    size_t pbase = ((size_t)(b * WP + y0 + ty + 1) * WP + (x0 + tx + 1)) * 64;
#pragma unroll
    for (int k = 0; k < 49; ++k) {
        float v = acc[k];
        v = (v > 0.f) ? v : 0.1f * v;           // leaky_relu(0.1)
        v *= 0.0078125f;                        // / 128
        unsigned short h = f2bf(v);
        xin_hi[pbase + k] = h;
        xin_lo[pbase + k] = f2bf(v - bf2f(h));
    }
#pragma unroll
    for (int k = 50; k < 64; ++k) { xin_hi[pbase + k] = 0; xin_lo[pbase + k] = 0; }
}

// ---------------- split-bf16 MFMA 3x3 conv + bias + leaky_relu ----------------
// kc-OUTER / tap-INNER: weights for all 9 taps of one 32-ch slice staged in LDS
// (XOR-swizzled ch-group slot -> 2-way banks = free). The 9-tap A re-reads then
// hit a per-XCD L2 working set of rows x 32-ch slice (~2.7 MB < 4 MiB), instead
// of the full-channel image (10.6 MB) that thrashed L2 in the tap-outer form.
// Barriers: 2 per kc chunk (vs 18 per block before).
template<int CIN, int COUT, int COB, int NCO, int OUTF>
__global__ __launch_bounds__(256, 2) void k_convM(
    const unsigned short* __restrict__ in_hi, const unsigned short* __restrict__ in_lo,
    const unsigned short* __restrict__ w_hi,  const unsigned short* __restrict__ w_lo,
    const float* __restrict__ bias,
    unsigned short* __restrict__ out_hi, unsigned short* __restrict__ out_lo,
    float* __restrict__ out_f) {
    constexpr int NT = COB / 16;
    constexpr int NKC = CIN / 32;
    constexpr int WSZ = 9 * COB * 32;   // elements per (hi|lo) plane
    __shared__ unsigned short wl[2 * WSZ];
    const int bid = blockIdx.x;
    const int b = bid & 7;
    const int t = bid >> 3;
    const int co0 = (t % NCO) * COB;
    const int ybx = t / NCO;
    const int wave = threadIdx.x >> 6;
    const int lane = threadIdx.x & 63;
    const int y = ybx * 2 + (wave >> 1);   // interior row 0..159
    const int x0 = (wave & 1) * 80;
    const int m = lane & 15, q = lane >> 4;
    f32x4 acc[5][NT];
#pragma unroll
    for (int mt = 0; mt < 5; ++mt)
#pragma unroll
        for (int nt = 0; nt < NT; ++nt) acc[mt][nt] = (f32x4){0.f, 0.f, 0.f, 0.f};
    int abase[5];
#pragma unroll
    for (int mt = 0; mt < 5; ++mt)
        abase[mt] = ((b * WP + y) * WP + x0 + mt * 16 + m) * CIN + q * 8;

    for (int kc = 0; kc < NKC; ++kc) {
        __syncthreads();   // previous chunk's reads done before overwrite
        for (int i = threadIdx.x; i < 9 * COB * 4; i += 256) {
            int tap = i / (COB * 4);
            int rem = i - tap * (COB * 4);
            int co = rem >> 2, g = rem & 3;
            int src = (tap * COUT + co0 + co) * CIN + kc * 32 + g * 8;
            int slot = (g + (co >> 1)) & 3;   // XOR/rotate swizzle: 2-way banks
            int dst = (tap * COB + co) * 32 + slot * 8;
            *(bf16x8*)&wl[dst] = *(const bf16x8*)&w_hi[src];
            *(bf16x8*)&wl[WSZ + dst] = *(const bf16x8*)&w_lo[src];
        }
        __syncthreads();
#pragma unroll
        for (int tap = 0; tap < 9; ++tap) {
            const int aoff = ((tap / 3) * WP + (tap % 3)) * CIN + kc * 32;
            bf16x8 ah[5], al[5];
#pragma unroll
            for (int mt = 0; mt < 5; ++mt) {
                const int off = abase[mt] + aoff;
                ah[mt] = *(const bf16x8*)&in_hi[off];
                al[mt] = *(const bf16x8*)&in_lo[off];
            }
#pragma unroll
            for (int nt = 0; nt < NT; ++nt) {
                const int co = nt * 16 + m;
                const int slot = (q + (co >> 1)) & 3;
                const int woff = (tap * COB + co) * 32 + slot * 8;
                bf16x8 bh = *(const bf16x8*)&wl[woff];
                bf16x8 bl = *(const bf16x8*)&wl[WSZ + woff];
#pragma unroll
                for (int mt = 0; mt < 5; ++mt) {
                    acc[mt][nt] = __builtin_amdgcn_mfma_f32_16x16x32_bf16(ah[mt], bh, acc[mt][nt], 0, 0, 0);
                    acc[mt][nt] = __builtin_amdgcn_mfma_f32_16x16x32_bf16(ah[mt], bl, acc[mt][nt], 0, 0, 0);
                    acc[mt][nt] = __builtin_amdgcn_mfma_f32_16x16x32_bf16(al[mt], bh, acc[mt][nt], 0, 0, 0);
                }
            }
        }
    }
    // epilogue: D col = lane&15 = co, D row = q*4+r = pixel within m-tile
#pragma unroll
    for (int nt = 0; nt < NT; ++nt) {
        const int co = co0 + nt * 16 + m;
        const float bv = bias[co];
#pragma unroll
        for (int mt = 0; mt < 5; ++mt) {
#pragma unroll
            for (int r = 0; r < 4; ++r) {
                float v = acc[mt][nt][r] + bv;
                v = (v > 0.f) ? v : 0.1f * v;
                const int x = x0 + mt * 16 + q * 4 + r;
                if (OUTF) {
                    out_f[((size_t)(b * COUT + co)) * HW + y * W + x] = v;
                } else {
                    const size_t off = ((size_t)(b * WP + y + 1) * WP + (x + 1)) * COUT + co;
                    unsigned short h = f2bf(v);
                    out_hi[off] = h;
                    out_lo[off] = f2bf(v - bf2f(h));
                }
            }
        }
    }
}

// ---------------- fused heads (5x5 convs) + warp + sigmoid ----------------
__global__ __launch_bounds__(256) void k_head(const float* __restrict__ x3,
                                              const float* __restrict__ wHT,
                                              const float* __restrict__ disp_b,
                                              const float* __restrict__ conf_b,
                                              const float* __restrict__ flow_up,
                                              float* __restrict__ out) {
    const int bid = blockIdx.x;
    const int b = bid & 7;
    const int t = bid >> 3;           // 0..99
    const int x0 = (t % 10) * 16, y0 = (t / 10) * 16;
    const int tx = threadIdx.x & 15, ty = threadIdx.x >> 4;
    const int tid = threadIdx.x;
    __shared__ float sh[2 * 400];  // 2 channels x 20x20
    float a0 = 0.f, a1 = 0.f, a2 = 0.f;
    const float* xb = x3 + (size_t)(b * 32) * HW;
    for (int ci = 0; ci < 32; ci += 2) {
        __syncthreads();
        for (int i = tid; i < 800; i += 256) {
            int cc = i / 400;
            int rem = i - cc * 400;
            int r = rem / 20, c2 = rem % 20;
            int gy = y0 + r - 2, gx = x0 + c2 - 2;
            float v = 0.f;
            if (gy >= 0 && gy < H && gx >= 0 && gx < W)
                v = xb[(size_t)(ci + cc) * HW + gy * W + gx];
            sh[i] = v;
        }
        __syncthreads();
#pragma unroll
        for (int cc = 0; cc < 2; ++cc) {
            const float* t2 = sh + cc * 400;
            const float* wp = wHT + (size_t)(ci + cc) * 75;
#pragma unroll
            for (int k = 0; k < 25; ++k) {
                float v = t2[(ty + k / 5) * 20 + tx + (k % 5)];
                a0 += v * wp[k * 3 + 0];
                a1 += v * wp[k * 3 + 1];
                a2 += v * wp[k * 3 + 2];
            }
        }
    }
    const int gx = x0 + tx, gy = y0 + ty;
    float d0 = a0 + disp_b[0];
    float d1 = a1 + disp_b[1];
    float cf = a2 + conf_b[0];
    cf = 1.f / (1.f + expf(-cf));

    float px = (float)gx + d0, py = (float)gy + d1;
    float x0f = floorf(px), y0f = floorf(py);
    float wx1 = px - x0f, wx0 = 1.f - wx1;
    float wy1 = py - y0f, wy0 = 1.f - wy1;
    const float* f0 = flow_up + (size_t)(b * 2) * HW;
    const float* f1 = f0 + HW;

    float m00, m01, m10, m11;
    float a00, a01, a10, a11;
    float b00, b01, b10, b11;
    auto corner = [&](float xf, float yf, float& m, float& c0, float& c1) {
        bool valid = (xf >= 0.f) && (xf <= (float)(W - 1)) && (yf >= 0.f) && (yf <= (float)(H - 1));
        m = valid ? 1.f : 0.f;
        if (valid) {
            int xi = (int)xf, yi = (int)yf;
            int o = yi * W + xi;
            c0 = f0[o]; c1 = f1[o];
        } else { c0 = 0.f; c1 = 0.f; }
    };
    corner(x0f,       y0f,       m00, a00, b00);
    corner(x0f + 1.f, y0f,       m01, a01, b01);
    corner(x0f,       y0f + 1.f, m10, a10, b10);
    corner(x0f + 1.f, y0f + 1.f, m11, a11, b11);

    float o0 = wy0 * (wx0 * a00 + wx1 * a01) + wy1 * (wx0 * a10 + wx1 * a11);
    float o1 = wy0 * (wx0 * b00 + wx1 * b01) + wy1 * (wx0 * b10 + wx1 * b11);
    float msk = wy0 * (wx0 * m00 + wx1 * m01) + wy1 * (wx0 * m10 + wx1 * m11);
    float mask = (msk >= 1.f) ? 1.f : 0.f;

    int o = gy * W + gx;
    out[(size_t)(b * 2 + 0) * HW + o] = o0 * mask;
    out[(size_t)(b * 2 + 1) * HW + o] = o1 * mask;
    out[(size_t)B * 2 * HW + (size_t)b * HW + o] = cf;
}

extern "C" void kernel_launch(void* const* d_in, const int* in_sizes, int n_in,
                              void* d_out, int out_size, void* d_ws, size_t ws_size,
                              hipStream_t stream) {
    const float* feats     = (const float*)d_in[0];
    const float* flow      = (const float*)d_in[1];
    const float* conf      = (const float*)d_in[2];
    const float* up_conf_w = (const float*)d_in[3];
    const float* up_flow_w = (const float*)d_in[4];
    const float* w1        = (const float*)d_in[5];
    const float* b1        = (const float*)d_in[6];
    const float* w2        = (const float*)d_in[7];
    const float* b2        = (const float*)d_in[8];
    const float* w3        = (const float*)d_in[9];
    const float* b3        = (const float*)d_in[10];
    const float* disp_w    = (const float*)d_in[11];
    const float* disp_b    = (const float*)d_in[12];
    const float* conf_w    = (const float*)d_in[13];
    const float* conf_b    = (const float*)d_in[14];
    float* out = (float*)d_out;

    // workspace layout (bytes)
    char* p = (char*)d_ws;
    const size_t SZ_XIN = (size_t)B * WP * WP * 64 * 2;    // 26,873,856 per buffer
    const size_t SZ_X1  = (size_t)B * WP * WP * 128 * 2;   // 53,747,712 per buffer
    unsigned short* xin_hi = (unsigned short*)p;
    unsigned short* xin_lo = (unsigned short*)(p + SZ_XIN);
    unsigned short* x1_hi  = (unsigned short*)(p + 2 * SZ_XIN);
    unsigned short* x1_lo  = (unsigned short*)(p + 2 * SZ_XIN + SZ_X1);
    char* p2 = p + 2 * SZ_XIN + 2 * SZ_X1;
    float* flow_up = (float*)p2;                 // 1,638,400 B
    float* wHT     = (float*)(p2 + 1638400);     // 9,600 B
    unsigned short* wpk1h = (unsigned short*)(p2 + 1648000);
    unsigned short* wpk1l = wpk1h + 73728;
    unsigned short* wpk2h = wpk1l + 73728;
    unsigned short* wpk2l = wpk2h + 73728;
    unsigned short* wpk3h = wpk2l + 73728;
    unsigned short* wpk3l = wpk3h + 18432;
    // aliases: x2 reuses xin (same geometry C=64, ring stays zero); x3 reuses x1_hi
    unsigned short* x2_hi = xin_hi;
    unsigned short* x2_lo = xin_lo;
    float* x3 = (float*)(p + 2 * SZ_XIN);        // 26.2 MB <= SZ_X1, x1 dead after conv2

    k_repack<<<658, 256, 0, stream>>>(w1, w2, w3, disp_w, conf_w,
                                      wpk1h, wpk1l, wpk2h, wpk2l, wpk3h, wpk3l, wHT);
    k_zeropad<<<484, 256, 0, stream>>>(xin_hi, xin_lo, x1_hi, x1_lo);
    k_upsample<<<(B * 3 * HW + 255) / 256, 256, 0, stream>>>(flow, conf, up_flow_w, up_conf_w,
                                                             flow_up, xin_hi, xin_lo);
    // 1-D grids: img = bid%8 pins each image to one XCD (round-robin dispatch)
    k_corr<<<800, 256, 0, stream>>>(feats, xin_hi, xin_lo);
    k_convM<64, 128, 64, 2, 0><<<1280, 256, 0, stream>>>(xin_hi, xin_lo, wpk1h, wpk1l, b1,
                                                         x1_hi, x1_lo, nullptr);
    k_convM<128, 64, 64, 1, 0><<<640, 256, 0, stream>>>(x1_hi, x1_lo, wpk2h, wpk2l, b2,
                                                        x2_hi, x2_lo, nullptr);
    k_convM<64, 32, 32, 1, 1><<<640, 256, 0, stream>>>(x2_hi, x2_lo, wpk3h, wpk3l, b3,
                                                       nullptr, nullptr, x3);
    k_head<<<800, 256, 0, stream>>>(x3, wHT, disp_b, conf_b, flow_up, out);
}

// Round 7
// 818.971 us; speedup vs baseline: 1.5440x; 1.1640x over previous
//
#include <hip/hip_runtime.h>
#include <math.h>

#define B 8
#define C 128
#define H 160
#define W 160
#define HW 25600
#define WP 162   // padded width/height (pad=1 ring of zeros)

typedef short bf16x8 __attribute__((ext_vector_type(8)));
typedef float f32x4  __attribute__((ext_vector_type(4)));

__device__ __forceinline__ unsigned short f2bf(float x) {  // RNE
    union { float f; unsigned u; } v; v.f = x;
    unsigned r = v.u + 0x7fff + ((v.u >> 16) & 1);
    return (unsigned short)(r >> 16);
}
__device__ __forceinline__ float bf2f(unsigned short h) {
    union { unsigned u; float f; } v; v.u = ((unsigned)h) << 16;
    return v.f;
}

// Activation layout ("chunk-pair interleaved", per padded pixel):
//   addr(px, ch, plane) = px*(2*C) + (ch>>5)*64 + plane*32 + (ch&31)
// One 32-ch chunk = 128 B = one L2 line holding hi(64B)|lo(64B) -> every
// fetched line is fully consumed by one wave in one tap.

// ---------------- weight repack: split-bf16 [tap][co][ci] ----------------
__global__ void k_repack(const float* __restrict__ w1, const float* __restrict__ w2,
                         const float* __restrict__ w3, const float* __restrict__ dw,
                         const float* __restrict__ cw,
                         unsigned short* __restrict__ wpk1h, unsigned short* __restrict__ wpk1l,
                         unsigned short* __restrict__ wpk2h, unsigned short* __restrict__ wpk2l,
                         unsigned short* __restrict__ wpk3h, unsigned short* __restrict__ wpk3l,
                         float* __restrict__ wHT) {
    int idx = blockIdx.x * 256 + threadIdx.x;
    if (idx < 73728) {  // w1: [t][co=128][ci=64]  (ci 0..49 real, 50..63 zero)
        int t = idx / 8192; int r = idx % 8192; int co = r / 64; int ci = r % 64;
        float v = (ci < 50) ? w1[(co * 50 + ci) * 9 + t] : 0.f;
        unsigned short h = f2bf(v);
        wpk1h[idx] = h; wpk1l[idx] = f2bf(v - bf2f(h));
        return;
    }
    idx -= 73728;
    if (idx < 73728) {  // w2: [t][co=64][ci=128]
        int t = idx / 8192; int r = idx % 8192; int co = r / 128; int ci = r % 128;
        float v = w2[(co * 128 + ci) * 9 + t];
        unsigned short h = f2bf(v);
        wpk2h[idx] = h; wpk2l[idx] = f2bf(v - bf2f(h));
        return;
    }
    idx -= 73728;
    if (idx < 18432) {  // w3: [t][co=32][ci=64]
        int t = idx / 2048; int r = idx % 2048; int co = r / 64; int ci = r % 64;
        float v = w3[(co * 64 + ci) * 9 + t];
        unsigned short h = f2bf(v);
        wpk3h[idx] = h; wpk3l[idx] = f2bf(v - bf2f(h));
        return;
    }
    idx -= 18432;
    if (idx < 2400) {   // heads (fp32): wHT[ci][k][3]: 0,1=disp 2=conf
        int ci = idx / 75; int rem = idx % 75; int k = rem / 3; int co = rem % 3;
        wHT[idx] = (co < 2) ? dw[(co * 32 + ci) * 25 + k] : cw[ci * 25 + k];
    }
}

// ---------------- zero the pad rings of xin (2C=128) and x1 (2C=256) ----------------
__global__ void k_zeropad(unsigned short* __restrict__ xin, unsigned short* __restrict__ x1) {
    int idx = blockIdx.x * 256 + threadIdx.x;
    unsigned short* p; int C2;
    if (idx < 82432) { p = xin; C2 = 128; }
    else {
        idx -= 82432;
        if (idx >= 164864) return;
        p = x1; C2 = 256;
    }
    int chunks = C2 / 8;
    int percnt = 644 * chunks;
    int img = idx / percnt;
    int r = idx % percnt;
    int rp = r / chunks; int ch = r % chunks;
    int yy, xx;
    if (rp < 162)      { yy = 0;   xx = rp; }
    else if (rp < 324) { yy = 161; xx = rp - 162; }
    else { int s = rp - 324; yy = 1 + (s >> 1); xx = (s & 1) ? 161 : 0; }
    size_t off = ((size_t)(img * WP + yy) * WP + xx) * C2 + ch * 8;
    bf16x8 z = {0, 0, 0, 0, 0, 0, 0, 0};
    *(bf16x8*)&p[off] = z;
}

// ---------------- deconv upsample (stride 2, pad 1, k=4) ----------------
__global__ void k_upsample(const float* __restrict__ flow, const float* __restrict__ conf,
                           const float* __restrict__ up_flow_w, const float* __restrict__ up_conf_w,
                           float* __restrict__ flow_up, unsigned short* __restrict__ xin) {
    int idx = blockIdx.x * 256 + threadIdx.x;
    if (idx >= B * 3 * HW) return;
    int x = idx % W;
    int y = (idx / W) % H;
    int ch = (idx / HW) % 3;
    int b = idx / (3 * HW);
    const float* in;
    const float* w;
    if (ch < 2) { in = flow + (size_t)(b * 2 + ch) * 6400; w = up_flow_w + ch * 16; }
    else        { in = conf + (size_t)b * 6400;            w = up_conf_w; }
    float acc = 0.f;
#pragma unroll
    for (int dy = 0; dy < 4; ++dy) {
        int tny = y + 1 - dy;
        if (tny < 0 || (tny & 1)) continue;
        int iy = tny >> 1;
        if (iy >= 80) continue;
#pragma unroll
        for (int dx = 0; dx < 4; ++dx) {
            int tnx = x + 1 - dx;
            if (tnx < 0 || (tnx & 1)) continue;
            int ix = tnx >> 1;
            if (ix >= 80) continue;
            acc += in[iy * 80 + ix] * w[dy * 4 + dx];
        }
    }
    if (ch < 2) flow_up[(size_t)(b * 2 + ch) * HW + y * W + x] = acc;
    else {
        // conf is channel 49: chunk 1, within 17
        size_t off = ((size_t)(b * WP + y + 1) * WP + (x + 1)) * 128 + 64 + 17;
        unsigned short h = f2bf(acc);
        xin[off] = h;
        xin[off + 32] = f2bf(acc - bf2f(h));
    }
}

// ---------------- dilated self-correlation (PATCH=7, DIL=2) ----------------
// 1 px/thread, acc[49], double-buffered channel staging, ONE barrier/channel.
__global__ __launch_bounds__(256, 4) void k_corr(const float* __restrict__ feats,
                                                 unsigned short* __restrict__ xin) {
    const int bid = blockIdx.x;
    const int b = bid & 7;
    const int t = bid >> 3;           // 0..99
    const int x0 = (t % 5) * 32;
    const int y0 = (t / 5) * 8;
    const int tid = threadIdx.x;
    const int tx = tid & 31;
    const int ty = tid >> 5;          // 0..7
    __shared__ float sh[2][880];      // 20 rows x 44 cols, double-buffered
    float acc[49];
#pragma unroll
    for (int i = 0; i < 49; ++i) acc[i] = 0.f;

    int soff[4]; bool sval[4];
#pragma unroll
    for (int s = 0; s < 4; ++s) {
        int i = tid + s * 256;
        int r = i / 44, cc = i % 44;
        int gy = y0 + r - 6, gx = x0 + cc - 6;
        sval[s] = (i < 880) && gy >= 0 && gy < H && gx >= 0 && gx < W;
        soff[s] = sval[s] ? (gy * W + gx) : 0;
    }
    const float* f = feats + (size_t)b * 2 * C * HW;  // feats[b, 0]
    float pre[4];
#pragma unroll
    for (int s = 0; s < 4; ++s) pre[s] = sval[s] ? f[soff[s]] : 0.f;

    for (int c = 0; c < C; ++c) {
        float* buf = sh[c & 1];
#pragma unroll
        for (int s = 0; s < 4; ++s) {
            int i = tid + s * 256;
            if (i < 880) buf[i] = pre[s];
        }
        if (c < C - 1) {
            const float* fn = f + (size_t)(c + 1) * HW;
#pragma unroll
            for (int s = 0; s < 4; ++s) pre[s] = sval[s] ? fn[soff[s]] : 0.f;
        }
        __syncthreads();
        float ctr = buf[(ty + 6) * 44 + tx + 6];
#pragma unroll
        for (int dy = 0; dy < 7; ++dy) {
            const float* row = &buf[(ty + 2 * dy) * 44 + tx];
#pragma unroll
            for (int dx = 0; dx < 7; ++dx)
                acc[dy * 7 + dx] += ctr * row[2 * dx];
        }
    }
    size_t pbase = ((size_t)(b * WP + y0 + ty + 1) * WP + (x0 + tx + 1)) * 128;
#pragma unroll
    for (int k = 0; k < 49; ++k) {
        float v = acc[k];
        v = (v > 0.f) ? v : 0.1f * v;           // leaky_relu(0.1)
        v *= 0.0078125f;                        // / 128
        unsigned short h = f2bf(v);
        size_t off = pbase + ((k >> 5) * 64) + (k & 31);
        xin[off] = h;
        xin[off + 32] = f2bf(v - bf2f(h));
    }
#pragma unroll
    for (int k = 50; k < 64; ++k) {
        size_t off = pbase + 64 + (k & 31);
        xin[off] = 0; xin[off + 32] = 0;
    }
}

// ---------------- split-bf16 MFMA 3x3 conv + bias + leaky_relu ----------------
// kc-outer / tap-inner. A-frags software-pipelined (tap t+1 prefetched into the
// other reg buffer during tap t's MFMAs; tap-0 loads overlap the W-staging
// barrier). A layout = chunk-pair interleaved: hi/lo of one kc slice share one
// 128-B line, fully consumed per access.
template<int CIN, int COUT, int COB, int NCO, int OUTF>
__global__ __launch_bounds__(256, 2) void k_convM(
    const unsigned short* __restrict__ in,
    const unsigned short* __restrict__ w_hi,  const unsigned short* __restrict__ w_lo,
    const float* __restrict__ bias,
    unsigned short* __restrict__ out_pk, float* __restrict__ out_f) {
    constexpr int NT = COB / 16;
    constexpr int NKC = CIN / 32;
    constexpr int CI2 = 2 * CIN;
    constexpr int WSZ = 9 * COB * 32;   // elements per (hi|lo) plane
    __shared__ unsigned short wl[2 * WSZ];
    const int bid = blockIdx.x;
    const int b = bid & 7;
    const int t = bid >> 3;
    const int co0 = (t % NCO) * COB;
    const int ybx = t / NCO;
    const int wave = threadIdx.x >> 6;
    const int lane = threadIdx.x & 63;
    const int y = ybx * 2 + (wave >> 1);   // interior row 0..159
    const int x0 = (wave & 1) * 80;
    const int m = lane & 15, q = lane >> 4;
    f32x4 acc[5][NT];
#pragma unroll
    for (int mt = 0; mt < 5; ++mt)
#pragma unroll
        for (int nt = 0; nt < NT; ++nt) acc[mt][nt] = (f32x4){0.f, 0.f, 0.f, 0.f};
    int abase[5];
#pragma unroll
    for (int mt = 0; mt < 5; ++mt)
        abase[mt] = ((b * WP + y) * WP + x0 + mt * 16 + m) * CI2 + q * 8;

    bf16x8 ah[2][5], al[2][5];

    for (int kc = 0; kc < NKC; ++kc) {
        __syncthreads();   // previous chunk's LDS reads done before overwrite
        // tap-0 A prefetch: issued before staging, drained by the barrier
        {
            const int aoff = kc * 64;   // tap 0: dy=0,dx=0
#pragma unroll
            for (int mt = 0; mt < 5; ++mt) {
                const unsigned short* pa = &in[abase[mt] + aoff];
                ah[0][mt] = *(const bf16x8*)pa;
                al[0][mt] = *(const bf16x8*)(pa + 32);
            }
        }
        for (int i = threadIdx.x; i < 9 * COB * 4; i += 256) {
            int tap = i / (COB * 4);
            int rem = i - tap * (COB * 4);
            int co = rem >> 2, g = rem & 3;
            int src = (tap * COUT + co0 + co) * CIN + kc * 32 + g * 8;
            int slot = (g + (co >> 1)) & 3;   // rotate swizzle: 2-way banks (free)
            int dst = (tap * COB + co) * 32 + slot * 8;
            *(bf16x8*)&wl[dst] = *(const bf16x8*)&w_hi[src];
            *(bf16x8*)&wl[WSZ + dst] = *(const bf16x8*)&w_lo[src];
        }
        __syncthreads();
#pragma unroll
        for (int tap = 0; tap < 9; ++tap) {
            const int cur = tap & 1, nxt = cur ^ 1;
            if (tap < 8) {   // prefetch tap+1 A-frags into the other buffer
                const int tap1 = tap + 1;
                const int aoff = ((tap1 / 3) * WP + (tap1 % 3)) * CI2 + kc * 64;
#pragma unroll
                for (int mt = 0; mt < 5; ++mt) {
                    const unsigned short* pa = &in[abase[mt] + aoff];
                    ah[nxt][mt] = *(const bf16x8*)pa;
                    al[nxt][mt] = *(const bf16x8*)(pa + 32);
                }
            }
#pragma unroll
            for (int nt = 0; nt < NT; ++nt) {
                const int co = nt * 16 + m;
                const int slot = (q + (co >> 1)) & 3;
                const int woff = (tap * COB + co) * 32 + slot * 8;
                bf16x8 bh = *(const bf16x8*)&wl[woff];
                bf16x8 bl = *(const bf16x8*)&wl[WSZ + woff];
#pragma unroll
                for (int mt = 0; mt < 5; ++mt) {
                    acc[mt][nt] = __builtin_amdgcn_mfma_f32_16x16x32_bf16(ah[cur][mt], bh, acc[mt][nt], 0, 0, 0);
                    acc[mt][nt] = __builtin_amdgcn_mfma_f32_16x16x32_bf16(ah[cur][mt], bl, acc[mt][nt], 0, 0, 0);
                    acc[mt][nt] = __builtin_amdgcn_mfma_f32_16x16x32_bf16(al[cur][mt], bh, acc[mt][nt], 0, 0, 0);
                }
            }
        }
    }
    // epilogue: D col = lane&15 = co, D row = q*4+r = pixel within m-tile
#pragma unroll
    for (int nt = 0; nt < NT; ++nt) {
        const int co = co0 + nt * 16 + m;
        const float bv = bias[co];
#pragma unroll
        for (int mt = 0; mt < 5; ++mt) {
#pragma unroll
            for (int r = 0; r < 4; ++r) {
                float v = acc[mt][nt][r] + bv;
                v = (v > 0.f) ? v : 0.1f * v;
                const int x = x0 + mt * 16 + q * 4 + r;
                if (OUTF) {
                    out_f[((size_t)(b * COUT + co)) * HW + y * W + x] = v;
                } else {
                    const size_t off = ((size_t)(b * WP + y + 1) * WP + (x + 1)) * (2 * COUT)
                                     + ((co >> 5) * 64) + (co & 31);
                    unsigned short h = f2bf(v);
                    out_pk[off] = h;
                    out_pk[off + 32] = f2bf(v - bf2f(h));
                }
            }
        }
    }
}

// ---------------- fused heads (5x5 convs) + warp + sigmoid ----------------
__global__ __launch_bounds__(256) void k_head(const float* __restrict__ x3,
                                              const float* __restrict__ wHT,
                                              const float* __restrict__ disp_b,
                                              const float* __restrict__ conf_b,
                                              const float* __restrict__ flow_up,
                                              float* __restrict__ out) {
    const int bid = blockIdx.x;
    const int b = bid & 7;
    const int t = bid >> 3;           // 0..99
    const int x0 = (t % 10) * 16, y0 = (t / 10) * 16;
    const int tx = threadIdx.x & 15, ty = threadIdx.x >> 4;
    const int tid = threadIdx.x;
    __shared__ float sh[2 * 400];  // 2 channels x 20x20
    float a0 = 0.f, a1 = 0.f, a2 = 0.f;
    const float* xb = x3 + (size_t)(b * 32) * HW;
    for (int ci = 0; ci < 32; ci += 2) {
        __syncthreads();
        for (int i = tid; i < 800; i += 256) {
            int cc = i / 400;
            int rem = i - cc * 400;
            int r = rem / 20, c2 = rem % 20;
            int gy = y0 + r - 2, gx = x0 + c2 - 2;
            float v = 0.f;
            if (gy >= 0 && gy < H && gx >= 0 && gx < W)
                v = xb[(size_t)(ci + cc) * HW + gy * W + gx];
            sh[i] = v;
        }
        __syncthreads();
#pragma unroll
        for (int cc = 0; cc < 2; ++cc) {
            const float* t2 = sh + cc * 400;
            const float* wp = wHT + (size_t)(ci + cc) * 75;
#pragma unroll
            for (int k = 0; k < 25; ++k) {
                float v = t2[(ty + k / 5) * 20 + tx + (k % 5)];
                a0 += v * wp[k * 3 + 0];
                a1 += v * wp[k * 3 + 1];
                a2 += v * wp[k * 3 + 2];
            }
        }
    }
    const int gx = x0 + tx, gy = y0 + ty;
    float d0 = a0 + disp_b[0];
    float d1 = a1 + disp_b[1];
    float cf = a2 + conf_b[0];
    cf = 1.f / (1.f + expf(-cf));

    float px = (float)gx + d0, py = (float)gy + d1;
    float x0f = floorf(px), y0f = floorf(py);
    float wx1 = px - x0f, wx0 = 1.f - wx1;
    float wy1 = py - y0f, wy0 = 1.f - wy1;
    const float* f0 = flow_up + (size_t)(b * 2) * HW;
    const float* f1 = f0 + HW;

    float m00, m01, m10, m11;
    float a00, a01, a10, a11;
    float b00, b01, b10, b11;
    auto corner = [&](float xf, float yf, float& m, float& c0, float& c1) {
        bool valid = (xf >= 0.f) && (xf <= (float)(W - 1)) && (yf >= 0.f) && (yf <= (float)(H - 1));
        m = valid ? 1.f : 0.f;
        if (valid) {
            int xi = (int)xf, yi = (int)yf;
            int o = yi * W + xi;
            c0 = f0[o]; c1 = f1[o];
        } else { c0 = 0.f; c1 = 0.f; }
    };
    corner(x0f,       y0f,       m00, a00, b00);
    corner(x0f + 1.f, y0f,       m01, a01, b01);
    corner(x0f,       y0f + 1.f, m10, a10, b10);
    corner(x0f + 1.f, y0f + 1.f, m11, a11, b11);

    float o0 = wy0 * (wx0 * a00 + wx1 * a01) + wy1 * (wx0 * a10 + wx1 * a11);
    float o1 = wy0 * (wx0 * b00 + wx1 * b01) + wy1 * (wx0 * b10 + wx1 * b11);
    float msk = wy0 * (wx0 * m00 + wx1 * m01) + wy1 * (wx0 * m10 + wx1 * m11);
    float mask = (msk >= 1.f) ? 1.f : 0.f;

    int o = gy * W + gx;
    out[(size_t)(b * 2 + 0) * HW + o] = o0 * mask;
    out[(size_t)(b * 2 + 1) * HW + o] = o1 * mask;
    out[(size_t)B * 2 * HW + (size_t)b * HW + o] = cf;
}

extern "C" void kernel_launch(void* const* d_in, const int* in_sizes, int n_in,
                              void* d_out, int out_size, void* d_ws, size_t ws_size,
                              hipStream_t stream) {
    const float* feats     = (const float*)d_in[0];
    const float* flow      = (const float*)d_in[1];
    const float* conf      = (const float*)d_in[2];
    const float* up_conf_w = (const float*)d_in[3];
    const float* up_flow_w = (const float*)d_in[4];
    const float* w1        = (const float*)d_in[5];
    const float* b1        = (const float*)d_in[6];
    const float* w2        = (const float*)d_in[7];
    const float* b2        = (const float*)d_in[8];
    const float* w3        = (const float*)d_in[9];
    const float* b3        = (const float*)d_in[10];
    const float* disp_w    = (const float*)d_in[11];
    const float* disp_b    = (const float*)d_in[12];
    const float* conf_w    = (const float*)d_in[13];
    const float* conf_b    = (const float*)d_in[14];
    float* out = (float*)d_out;

    // workspace layout (bytes)
    char* p = (char*)d_ws;
    const size_t SZ_XIN = (size_t)B * WP * WP * 128 * 2;   // 53,747,712 (hi|lo interleaved)
    const size_t SZ_X1  = (size_t)B * WP * WP * 256 * 2;   // 107,495,424
    unsigned short* xin = (unsigned short*)p;
    unsigned short* x1  = (unsigned short*)(p + SZ_XIN);
    char* p2 = p + SZ_XIN + SZ_X1;
    float* flow_up = (float*)p2;                 // 1,638,400 B
    float* wHT     = (float*)(p2 + 1638400);     // 9,600 B
    unsigned short* wpk1h = (unsigned short*)(p2 + 1648000);
    unsigned short* wpk1l = wpk1h + 73728;
    unsigned short* wpk2h = wpk1l + 73728;
    unsigned short* wpk2l = wpk2h + 73728;
    unsigned short* wpk3h = wpk2l + 73728;
    unsigned short* wpk3l = wpk3h + 18432;
    // aliases: x2 reuses xin (same geometry 2C=128, ring stays zero); x3 reuses x1
    unsigned short* x2 = xin;
    float* x3 = (float*)x1;   // 26.2 MB <= SZ_X1, x1 dead after conv2

    k_repack<<<658, 256, 0, stream>>>(w1, w2, w3, disp_w, conf_w,
                                      wpk1h, wpk1l, wpk2h, wpk2l, wpk3h, wpk3l, wHT);
    k_zeropad<<<966, 256, 0, stream>>>(xin, x1);
    k_upsample<<<(B * 3 * HW + 255) / 256, 256, 0, stream>>>(flow, conf, up_flow_w, up_conf_w,
                                                             flow_up, xin);
    // 1-D grids: img = bid&7 pins each image to one XCD (round-robin dispatch)
    k_corr<<<800, 256, 0, stream>>>(feats, xin);
    k_convM<64, 128, 64, 2, 0><<<1280, 256, 0, stream>>>(xin, wpk1h, wpk1l, b1, x1, nullptr);
    k_convM<128, 64, 64, 1, 0><<<640, 256, 0, stream>>>(x1, wpk2h, wpk2l, b2, x2, nullptr);
    k_convM<64, 32, 32, 1, 1><<<640, 256, 0, stream>>>(x2, wpk3h, wpk3l, b3, nullptr, x3);
    k_head<<<800, 256, 0, stream>>>(x3, wHT, disp_b, conf_b, flow_up, out);
}